// Round 11
// baseline (383.040 us; speedup 1.0000x reference)
//
#include <hip/hip_runtime.h>

#define NN 50000
#define EE 800000
#define ETOT (EE + NN)
#define GG 256
#define LL 3
#define HH 4
#define DD 128
#define NBLK ((NN + 255) / 256)   // 196
#define NXCD 8
#define DPX ((NN + NXCD - 1) / NXCD)  // 6250
#define CSRB 1024

#define NEG_SENT (-1e30f)

// float -> bf16 bits (round-nearest-even), finite inputs.
__device__ __forceinline__ unsigned short f2bf(float x) {
  unsigned u = __float_as_uint(x);
  unsigned r = u + 0x7FFFu + ((u >> 16) & 1u);
  return (unsigned short)(r >> 16);
}

// ---- GEMM + attention-logit epilogue (padded sA, bf16 W in LDS) ----
__global__ __launch_bounds__(256) void gemm_al_k(const float* __restrict__ A,
                                                 const float* __restrict__ Wl,
                                                 const float* __restrict__ asrc,
                                                 const float* __restrict__ adst,
                                                 unsigned short* __restrict__ Hb,
                                                 float* __restrict__ al_s,
                                                 float* __restrict__ al_d) {
  __shared__ unsigned short sWb[128 * 128];  // 32 KB bf16
  __shared__ float sA[32][132];              // padded: 132%32=4
  int tid = threadIdx.x;
#pragma unroll
  for (int j = 0; j < 16; ++j) {
    int idx = j * 256 + tid;
    float4 v = *(const float4*)&Wl[idx * 4];
    uint2 p;
    p.x = (unsigned)f2bf(v.x) | ((unsigned)f2bf(v.y) << 16);
    p.y = (unsigned)f2bf(v.z) | ((unsigned)f2bf(v.w) << 16);
    *(uint2*)&sWb[idx * 4] = p;
  }
  int row0 = blockIdx.x * 32;
#pragma unroll
  for (int j = 0; j < 4; ++j) {
    int idx = j * 256 + tid;
    int r = idx >> 5, c4 = idx & 31;
    int gr = row0 + r;
    float4 v = (gr < NN) ? *(const float4*)&A[(size_t)gr * DD + c4 * 4]
                         : make_float4(0.f, 0.f, 0.f, 0.f);
    *(float4*)&sA[r][c4 * 4] = v;
  }
  __syncthreads();
  int tc = tid & 31;
  int tr = tid >> 5;
  float acc[4][4] = {};
  for (int k = 0; k < 128; ++k) {
    uint2 wp = *(const uint2*)&sWb[k * 128 + tc * 4];
    float w0 = __uint_as_float(wp.x << 16);
    float w1 = __uint_as_float(wp.x & 0xFFFF0000u);
    float w2 = __uint_as_float(wp.y << 16);
    float w3 = __uint_as_float(wp.y & 0xFFFF0000u);
    float a[4];
#pragma unroll
    for (int r = 0; r < 4; ++r) a[r] = sA[tr * 4 + r][k];
#pragma unroll
    for (int r = 0; r < 4; ++r) {
      acc[r][0] = __fmaf_rn(a[r], w0, acc[r][0]);
      acc[r][1] = __fmaf_rn(a[r], w1, acc[r][1]);
      acc[r][2] = __fmaf_rn(a[r], w2, acc[r][2]);
      acc[r][3] = __fmaf_rn(a[r], w3, acc[r][3]);
    }
  }
  float4 as4 = *(const float4*)&asrc[tc * 4];
  float4 ad4 = *(const float4*)&adst[tc * 4];
  int hg = tc >> 3;
  float ps[4], pd[4];
#pragma unroll
  for (int r = 0; r < 4; ++r) {
    ps[r] = acc[r][0] * as4.x + acc[r][1] * as4.y + acc[r][2] * as4.z + acc[r][3] * as4.w;
    pd[r] = acc[r][0] * ad4.x + acc[r][1] * ad4.y + acc[r][2] * ad4.z + acc[r][3] * ad4.w;
  }
#pragma unroll
  for (int off = 4; off; off >>= 1) {
#pragma unroll
    for (int r = 0; r < 4; ++r) {
      ps[r] += __shfl_xor(ps[r], off);
      pd[r] += __shfl_xor(pd[r], off);
    }
  }
#pragma unroll
  for (int r = 0; r < 4; ++r) {
    int gr = row0 + tr * 4 + r;
    if (gr < NN) {
      unsigned lo = (unsigned)f2bf(acc[r][0]) | ((unsigned)f2bf(acc[r][1]) << 16);
      unsigned hi = (unsigned)f2bf(acc[r][2]) | ((unsigned)f2bf(acc[r][3]) << 16);
      uint2 w = {lo, hi};
      *(uint2*)&Hb[(size_t)gr * DD + tc * 4] = w;
      if ((tc & 7) == 0) {
        al_s[gr * 4 + hg] = ps[r];
        al_d[gr * 4 + hg] = pd[r];
      }
    }
  }
}

// ---- CSR build: XCD-affine dst-range partitioning ----
__global__ __launch_bounds__(256) void deg_k(const int* __restrict__ ei,
                                             int* __restrict__ deg) {
  int lo = (blockIdx.x & 7) * DPX, hi = lo + DPX;
  int stride = (gridDim.x >> 3) * 256;
  for (int e = (blockIdx.x >> 3) * 256 + threadIdx.x; e < ETOT; e += stride) {
    int d = (e < EE) ? ei[EE + e] : (e - EE);
    if (d >= lo && d < hi) atomicAdd(&deg[d], 1);
  }
}

__global__ __launch_bounds__(256) void scanA_k(const int* __restrict__ deg,
                                               int* __restrict__ rp,
                                               int* __restrict__ bsum) {
  __shared__ int sb[256];
  int t = threadIdx.x, b = blockIdx.x, i = b * 256 + t;
  int d = (i < NN) ? deg[i] : 0;
  sb[t] = d;
  __syncthreads();
#pragma unroll
  for (int off = 1; off < 256; off <<= 1) {
    int v = (t >= off) ? sb[t - off] : 0;
    __syncthreads();
    sb[t] += v;
    __syncthreads();
  }
  if (i < NN) rp[i] = sb[t] - d;
  if (t == 255) bsum[b] = sb[255];
}

// Block-total scan + graph-start binary searches fused (one small block).
__global__ __launch_bounds__(256) void scanB_k(const int* __restrict__ bsum,
                                               int* __restrict__ boff,
                                               const int* __restrict__ batch,
                                               int* __restrict__ gs) {
  __shared__ int sb[256];
  int t = threadIdx.x;
  int d = (t < NBLK) ? bsum[t] : 0;
  sb[t] = d;
  __syncthreads();
#pragma unroll
  for (int off = 1; off < 256; off <<= 1) {
    int v = (t >= off) ? sb[t - off] : 0;
    __syncthreads();
    sb[t] += v;
    __syncthreads();
  }
  if (t < NBLK) boff[t] = sb[t] - d;
  for (int g = t; g <= GG; g += 256) {
    int lo = 0, hi = NN;
    while (lo < hi) {
      int mid = (lo + hi) >> 1;
      if (batch[mid] < g) lo = mid + 1; else hi = mid;
    }
    gs[g] = lo;
  }
}

__global__ __launch_bounds__(256) void scanC_k(int* __restrict__ rp,
                                               const int* __restrict__ boff,
                                               int* __restrict__ cur) {
  int b = blockIdx.x, i = b * 256 + threadIdx.x;
  if (i < NN) {
    int v = rp[i] + boff[b];
    rp[i] = v;
    cur[i] = v;
  }
  if (i == 0) rp[NN] = ETOT;
}

__global__ __launch_bounds__(256) void scatter_k(const int* __restrict__ ei,
                                                 int* __restrict__ cur,
                                                 int* __restrict__ col) {
  int lo = (blockIdx.x & 7) * DPX, hi = lo + DPX;
  int stride = (gridDim.x >> 3) * 256;
  for (int e = (blockIdx.x >> 3) * 256 + threadIdx.x; e < ETOT; e += stride) {
    int d = (e < EE) ? ei[EE + e] : (e - EE);
    if (d >= lo && d < hi) {
      int s = (e < EE) ? ei[e] : d;
      int pos = atomicAdd(&cur[d], 1);
      col[pos] = s;
    }
  }
}

// ---- Fused per-node: segment-softmax (direct exp) + weighted agg
//      (8 edge slots, 16 feats/lane via 2x uint4) + bias+LN+LeakyReLU ----
__global__ __launch_bounds__(256) void agg_k(const int* __restrict__ rp,
                                             const int* __restrict__ col,
                                             const float* __restrict__ als,
                                             const float* __restrict__ ald,
                                             const unsigned short* __restrict__ Hb,
                                             const float* __restrict__ bias,
                                             const float* __restrict__ gamma,
                                             const float* __restrict__ beta,
                                             float* __restrict__ outb) {
  __shared__ float salpha[4][4][68];  // stride 68 -> max 2-way bank alias (free)
  __shared__ int   scol[4][64];
  int wave = threadIdx.x >> 6, lane = threadIdx.x & 63;
  int n = blockIdx.x * 4 + wave;
  if (n >= NN) return;
  int e0 = rp[n], e1 = rp[n + 1];
  int deg = e1 - e0;
  float4 ad = *(const float4*)&ald[(size_t)n * 4];

  if (deg <= 64) {
    // --- softmax: one edge per lane, direct exp (clamp@60) ---
    int sn = (lane < deg) ? col[e0 + lane] : -1;
    float4 as;
    if (sn >= 0) as = *(const float4*)&als[(size_t)sn * 4];
    else         as = make_float4(0.f, 0.f, 0.f, 0.f);
    float v0 = as.x + ad.x, v1 = as.y + ad.y, v2 = as.z + ad.z, v3 = as.w + ad.w;
    v0 = v0 > 0.f ? v0 : 0.2f * v0;
    v1 = v1 > 0.f ? v1 : 0.2f * v1;
    v2 = v2 > 0.f ? v2 : 0.2f * v2;
    v3 = v3 > 0.f ? v3 : 0.2f * v3;
    float p0 = (sn >= 0) ? __expf(fminf(v0, 60.f)) : 0.f;
    float p1 = (sn >= 0) ? __expf(fminf(v1, 60.f)) : 0.f;
    float p2 = (sn >= 0) ? __expf(fminf(v2, 60.f)) : 0.f;
    float p3 = (sn >= 0) ? __expf(fminf(v3, 60.f)) : 0.f;
    float s0 = p0, s1 = p1, s2 = p2, s3 = p3;
#pragma unroll
    for (int off = 32; off; off >>= 1) {
      s0 += __shfl_xor(s0, off);
      s1 += __shfl_xor(s1, off);
      s2 += __shfl_xor(s2, off);
      s3 += __shfl_xor(s3, off);
    }
    scol[wave][lane] = sn;
    salpha[wave][0][lane] = __fdividef(p0, s0);
    salpha[wave][1][lane] = __fdividef(p1, s1);
    salpha[wave][2][lane] = __fdividef(p2, s2);
    salpha[wave][3][lane] = __fdividef(p3, s3);
    asm volatile("s_waitcnt lgkmcnt(0)" ::: "memory");

    // --- gather: sub = lane>>3 (8 edge slots), fl = lane&7 (16 feats/lane) ---
    int sub = lane >> 3, fl = lane & 7;
    int hh2 = fl >> 1;  // head of this 16-feature block
    float b[16];
#pragma unroll
    for (int q = 0; q < 16; ++q) b[q] = 0.f;
#pragma unroll 2
    for (int j = sub; j < deg; j += 8) {
      int snj = scol[wave][j];
      float alpha = salpha[wave][hh2][j];
      const unsigned short* hp = &Hb[(size_t)snj * DD + fl * 16];
      uint4 pA = *(const uint4*)hp;
      uint4 pB = *(const uint4*)(hp + 8);
      b[0]  = __fmaf_rn(alpha, __uint_as_float(pA.x << 16),         b[0]);
      b[1]  = __fmaf_rn(alpha, __uint_as_float(pA.x & 0xFFFF0000u), b[1]);
      b[2]  = __fmaf_rn(alpha, __uint_as_float(pA.y << 16),         b[2]);
      b[3]  = __fmaf_rn(alpha, __uint_as_float(pA.y & 0xFFFF0000u), b[3]);
      b[4]  = __fmaf_rn(alpha, __uint_as_float(pA.z << 16),         b[4]);
      b[5]  = __fmaf_rn(alpha, __uint_as_float(pA.z & 0xFFFF0000u), b[5]);
      b[6]  = __fmaf_rn(alpha, __uint_as_float(pA.w << 16),         b[6]);
      b[7]  = __fmaf_rn(alpha, __uint_as_float(pA.w & 0xFFFF0000u), b[7]);
      b[8]  = __fmaf_rn(alpha, __uint_as_float(pB.x << 16),         b[8]);
      b[9]  = __fmaf_rn(alpha, __uint_as_float(pB.x & 0xFFFF0000u), b[9]);
      b[10] = __fmaf_rn(alpha, __uint_as_float(pB.y << 16),         b[10]);
      b[11] = __fmaf_rn(alpha, __uint_as_float(pB.y & 0xFFFF0000u), b[11]);
      b[12] = __fmaf_rn(alpha, __uint_as_float(pB.z << 16),         b[12]);
      b[13] = __fmaf_rn(alpha, __uint_as_float(pB.z & 0xFFFF0000u), b[13]);
      b[14] = __fmaf_rn(alpha, __uint_as_float(pB.w << 16),         b[14]);
      b[15] = __fmaf_rn(alpha, __uint_as_float(pB.w & 0xFFFF0000u), b[15]);
    }
    // combine the 8 edge-slot partials (lanes sharing fl: xor 32,16,8)
#pragma unroll
    for (int q = 0; q < 16; ++q) {
      b[q] += __shfl_xor(b[q], 32);
      b[q] += __shfl_xor(b[q], 16);
      b[q] += __shfl_xor(b[q], 8);
    }

    // bias + LayerNorm + LeakyReLU; reduce over the 8 fl lanes (xor 4,2,1)
    int f16 = fl * 16;
    float x[16];
    float sum = 0.f, ssq = 0.f;
#pragma unroll
    for (int q4 = 0; q4 < 4; ++q4) {
      float4 bi = *(const float4*)&bias[f16 + q4 * 4];
      float bb[4] = {bi.x, bi.y, bi.z, bi.w};
#pragma unroll
      for (int r = 0; r < 4; ++r) {
        float xv = b[q4 * 4 + r] + bb[r];
        x[q4 * 4 + r] = xv;
        sum += xv;
        ssq = __fmaf_rn(xv, xv, ssq);
      }
    }
#pragma unroll
    for (int off = 4; off; off >>= 1) {
      sum += __shfl_xor(sum, off);
      ssq += __shfl_xor(ssq, off);
    }
    float mu = sum * (1.f / 128.f);
    float var = ssq * (1.f / 128.f) - mu * mu;
    float rstd = rsqrtf(var + 1e-5f);
    if (sub == 0) {
#pragma unroll
      for (int q4 = 0; q4 < 4; ++q4) {
        float4 ga = *(const float4*)&gamma[f16 + q4 * 4];
        float4 be = *(const float4*)&beta[f16 + q4 * 4];
        float gg[4] = {ga.x, ga.y, ga.z, ga.w};
        float eb[4] = {be.x, be.y, be.z, be.w};
        float4 o;
        float yv[4];
#pragma unroll
        for (int r = 0; r < 4; ++r) {
          float y = (x[q4 * 4 + r] - mu) * rstd * gg[r] + eb[r];
          yv[r] = y > 0.f ? y : 0.1f * y;
        }
        o.x = yv[0]; o.y = yv[1]; o.z = yv[2]; o.w = yv[3];
        *(float4*)&outb[(size_t)n * DD + f16 + q4 * 4] = o;
      }
    }
  } else {
    // --- fallback: two-pass direct-exp, 2 feats/lane (deg>64; ~never taken) ---
    int hh = lane >> 4;
    float a0 = 0.f, a1 = 0.f;
    float s[4] = {0.f, 0.f, 0.f, 0.f};
    for (int e = e0 + lane; e < e1; e += 64) {
      int sn = col[e];
      float4 as = *(const float4*)&als[(size_t)sn * 4];
      float v[4] = {as.x + ad.x, as.y + ad.y, as.z + ad.z, as.w + ad.w};
#pragma unroll
      for (int h = 0; h < 4; ++h) {
        float vv = v[h] > 0.f ? v[h] : 0.2f * v[h];
        s[h] += __expf(fminf(vv, 60.f));
      }
    }
#pragma unroll
    for (int off = 32; off; off >>= 1) {
#pragma unroll
      for (int h = 0; h < 4; ++h) s[h] += __shfl_xor(s[h], off);
    }
    float rdh = __fdividef(1.f, s[hh]);
    float adh = (hh == 0) ? ad.x : (hh == 1) ? ad.y : (hh == 2) ? ad.z : ad.w;
    int e = e0;
    while (e < e1) {
      int cnt = min(64, e1 - e);
      int myS = (lane < cnt) ? col[e + lane] : 0;
      for (int j = 0; j < cnt; ++j) {
        int sn = __shfl(myS, j);
        float v = als[(size_t)sn * 4 + hh] + adh;
        v = v > 0.f ? v : 0.2f * v;
        float alpha = __expf(fminf(v, 60.f)) * rdh;
        unsigned pck = *(const unsigned*)&Hb[(size_t)sn * DD + 2 * lane];
        float h0 = __uint_as_float(pck << 16);
        float h1 = __uint_as_float(pck & 0xFFFF0000u);
        a0 = __fmaf_rn(alpha, h0, a0);
        a1 = __fmaf_rn(alpha, h1, a1);
      }
      e += cnt;
    }
    int f0 = 2 * lane, f1 = 2 * lane + 1;
    float x0 = a0 + bias[f0], x1 = a1 + bias[f1];
    float sum = x0 + x1, ssq = x0 * x0 + x1 * x1;
#pragma unroll
    for (int off = 32; off; off >>= 1) {
      sum += __shfl_xor(sum, off);
      ssq += __shfl_xor(ssq, off);
    }
    float mu = sum * (1.f / 128.f);
    float var = ssq * (1.f / 128.f) - mu * mu;
    float rstd = rsqrtf(var + 1e-5f);
    float y0 = (x0 - mu) * rstd * gamma[f0] + beta[f0];
    float y1 = (x1 - mu) * rstd * gamma[f1] + beta[f1];
    y0 = y0 > 0.f ? y0 : 0.1f * y0;
    y1 = y1 > 0.f ? y1 : 0.1f * y1;
    float2 o = {y0, y1};
    *(float2*)&outb[(size_t)n * DD + f0] = o;
  }
}

// ---- Fused pooling + output GEMM ----
__global__ __launch_bounds__(256) void poolout_k(const float* __restrict__ xin,
                                                 const int* __restrict__ gs,
                                                 const float* __restrict__ Wout,
                                                 const float* __restrict__ bout,
                                                 float* __restrict__ out) {
  __shared__ float sp[256];
  __shared__ float r0[256], r1[256];
  int g = blockIdx.x, t = threadIdx.x;
  int f = t & 127, half = t >> 7;
  int n0 = gs[g], n1 = gs[g + 1];
  int cnt = n1 - n0;
  int mid = n0 + (cnt >> 1);
  int a = half ? mid : n0;
  int b = half ? n1 : mid;
  float mx = NEG_SENT, sm = 0.f;
  for (int n = a; n < b; ++n) {
    float v = xin[(size_t)n * DD + f];
    mx = fmaxf(mx, v);
    sm += v;
  }
  r0[t] = mx;
  r1[t] = sm;
  __syncthreads();
  if (t < 128) {
    sp[t] = fmaxf(r0[t], r0[t + 128]);
    sp[128 + t] = (r1[t] + r1[t + 128]) / fmaxf((float)cnt, 1.f);
  }
  __syncthreads();
  float acc = half ? 0.f : bout[f];
  int k0 = half * 128;
#pragma unroll 8
  for (int k = k0; k < k0 + 128; ++k) acc = __fmaf_rn(sp[k], Wout[k * 128 + f], acc);
  r0[t] = acc;
  __syncthreads();
  if (t < 128) out[(size_t)g * 128 + f] = r0[t] + r0[t + 128];
}

extern "C" void kernel_launch(void* const* d_in, const int* in_sizes, int n_in,
                              void* d_out, int out_size, void* d_ws, size_t ws_size,
                              hipStream_t stream) {
  const float* x       = (const float*)d_in[0];
  const int*   ei      = (const int*)d_in[1];
  const int*   batch   = (const int*)d_in[2];
  const float* W       = (const float*)d_in[3];
  const float* att_src = (const float*)d_in[4];
  const float* att_dst = (const float*)d_in[5];
  const float* bias    = (const float*)d_in[6];
  const float* gamma   = (const float*)d_in[7];
  const float* beta    = (const float*)d_in[8];
  const float* Wout    = (const float*)d_in[9];
  const float* bout    = (const float*)d_in[10];
  float* out = (float*)d_out;

  char* ws = (char*)d_ws;
  unsigned short* Hb = (unsigned short*)ws; ws += (size_t)NN * DD * 2;
  float* AB   = (float*)ws; ws += (size_t)NN * DD * 4;
  float* als  = (float*)ws; ws += (size_t)NN * HH * 4;
  float* ald  = (float*)ws; ws += (size_t)NN * HH * 4;
  int*   rp   = (int*)ws;   ws += (size_t)(NN + 1) * 4;
  int*   deg  = (int*)ws;   ws += (size_t)NN * 4;      // reused as scatter cursor
  int*   col  = (int*)ws;   ws += (size_t)ETOT * 4;
  int*   gs   = (int*)ws;   ws += (size_t)(GG + 1) * 4;
  int*   bsum = (int*)ws;   ws += (size_t)NBLK * 4;
  int*   boff = (int*)ws;   ws += (size_t)NBLK * 4;

  // ---- CSR build + graph offsets (once) ----
  hipMemsetAsync(deg, 0, (size_t)NN * 4, stream);
  deg_k<<<CSRB, 256, 0, stream>>>(ei, deg);
  scanA_k<<<NBLK, 256, 0, stream>>>(deg, rp, bsum);
  scanB_k<<<1, 256, 0, stream>>>(bsum, boff, batch, gs);
  scanC_k<<<NBLK, 256, 0, stream>>>(rp, boff, deg);
  scatter_k<<<CSRB, 256, 0, stream>>>(ei, deg, col);

  // ---- layers ----
  const float* in = x;
  for (int l = 0; l < LL; ++l) {
    gemm_al_k<<<(NN + 31) / 32, 256, 0, stream>>>(in, W + (size_t)l * DD * DD,
                                                  att_src + l * DD, att_dst + l * DD,
                                                  Hb, als, ald);
    agg_k<<<(NN + 3) / 4, 256, 0, stream>>>(rp, col, als, ald, Hb,
                                            bias + l * DD, gamma + l * DD, beta + l * DD, AB);
    in = AB;
  }

  // ---- fused pooling + output GEMM ----
  poolout_k<<<GG, 256, 0, stream>>>(AB, gs, Wout, bout, out);
}

// Round 12
// 360.033 us; speedup vs baseline: 1.0639x; 1.0639x over previous
//
#include <hip/hip_runtime.h>

#define NN 50000
#define EE 800000
#define ETOT (EE + NN)
#define GG 256
#define LL 3
#define HH 4
#define DD 128
#define NBLK ((NN + 255) / 256)   // 196
#define NXCD 8
#define DPX ((NN + NXCD - 1) / NXCD)  // 6250
#define CSRB 1024

#define NEG_SENT (-1e30f)

// float -> bf16 bits (round-nearest-even), finite inputs.
__device__ __forceinline__ unsigned short f2bf(float x) {
  unsigned u = __float_as_uint(x);
  unsigned r = u + 0x7FFFu + ((u >> 16) & 1u);
  return (unsigned short)(r >> 16);
}

// ---- GEMM + attention-logit epilogue (padded sA, bf16 W in LDS) ----
__global__ __launch_bounds__(256) void gemm_al_k(const float* __restrict__ A,
                                                 const float* __restrict__ Wl,
                                                 const float* __restrict__ asrc,
                                                 const float* __restrict__ adst,
                                                 unsigned short* __restrict__ Hb,
                                                 float* __restrict__ al_s,
                                                 float* __restrict__ al_d) {
  __shared__ unsigned short sWb[128 * 128];  // 32 KB bf16
  __shared__ float sA[32][132];              // padded: 132%32=4
  int tid = threadIdx.x;
#pragma unroll
  for (int j = 0; j < 16; ++j) {
    int idx = j * 256 + tid;
    float4 v = *(const float4*)&Wl[idx * 4];
    uint2 p;
    p.x = (unsigned)f2bf(v.x) | ((unsigned)f2bf(v.y) << 16);
    p.y = (unsigned)f2bf(v.z) | ((unsigned)f2bf(v.w) << 16);
    *(uint2*)&sWb[idx * 4] = p;
  }
  int row0 = blockIdx.x * 32;
#pragma unroll
  for (int j = 0; j < 4; ++j) {
    int idx = j * 256 + tid;
    int r = idx >> 5, c4 = idx & 31;
    int gr = row0 + r;
    float4 v = (gr < NN) ? *(const float4*)&A[(size_t)gr * DD + c4 * 4]
                         : make_float4(0.f, 0.f, 0.f, 0.f);
    *(float4*)&sA[r][c4 * 4] = v;
  }
  __syncthreads();
  int tc = tid & 31;
  int tr = tid >> 5;
  float acc[4][4] = {};
  for (int k = 0; k < 128; ++k) {
    uint2 wp = *(const uint2*)&sWb[k * 128 + tc * 4];
    float w0 = __uint_as_float(wp.x << 16);
    float w1 = __uint_as_float(wp.x & 0xFFFF0000u);
    float w2 = __uint_as_float(wp.y << 16);
    float w3 = __uint_as_float(wp.y & 0xFFFF0000u);
    float a[4];
#pragma unroll
    for (int r = 0; r < 4; ++r) a[r] = sA[tr * 4 + r][k];
#pragma unroll
    for (int r = 0; r < 4; ++r) {
      acc[r][0] = __fmaf_rn(a[r], w0, acc[r][0]);
      acc[r][1] = __fmaf_rn(a[r], w1, acc[r][1]);
      acc[r][2] = __fmaf_rn(a[r], w2, acc[r][2]);
      acc[r][3] = __fmaf_rn(a[r], w3, acc[r][3]);
    }
  }
  float4 as4 = *(const float4*)&asrc[tc * 4];
  float4 ad4 = *(const float4*)&adst[tc * 4];
  int hg = tc >> 3;
  float ps[4], pd[4];
#pragma unroll
  for (int r = 0; r < 4; ++r) {
    ps[r] = acc[r][0] * as4.x + acc[r][1] * as4.y + acc[r][2] * as4.z + acc[r][3] * as4.w;
    pd[r] = acc[r][0] * ad4.x + acc[r][1] * ad4.y + acc[r][2] * ad4.z + acc[r][3] * ad4.w;
  }
#pragma unroll
  for (int off = 4; off; off >>= 1) {
#pragma unroll
    for (int r = 0; r < 4; ++r) {
      ps[r] += __shfl_xor(ps[r], off);
      pd[r] += __shfl_xor(pd[r], off);
    }
  }
#pragma unroll
  for (int r = 0; r < 4; ++r) {
    int gr = row0 + tr * 4 + r;
    if (gr < NN) {
      unsigned lo = (unsigned)f2bf(acc[r][0]) | ((unsigned)f2bf(acc[r][1]) << 16);
      unsigned hi = (unsigned)f2bf(acc[r][2]) | ((unsigned)f2bf(acc[r][3]) << 16);
      uint2 w = {lo, hi};
      *(uint2*)&Hb[(size_t)gr * DD + tc * 4] = w;
      if ((tc & 7) == 0) {
        al_s[gr * 4 + hg] = ps[r];
        al_d[gr * 4 + hg] = pd[r];
      }
    }
  }
}

// ---- CSR build: XCD-affine dst-range partitioning ----
__global__ __launch_bounds__(256) void deg_k(const int* __restrict__ ei,
                                             int* __restrict__ deg) {
  int lo = (blockIdx.x & 7) * DPX, hi = lo + DPX;
  int stride = (gridDim.x >> 3) * 256;
  for (int e = (blockIdx.x >> 3) * 256 + threadIdx.x; e < ETOT; e += stride) {
    int d = (e < EE) ? ei[EE + e] : (e - EE);
    if (d >= lo && d < hi) atomicAdd(&deg[d], 1);
  }
}

__global__ __launch_bounds__(256) void scanA_k(const int* __restrict__ deg,
                                               int* __restrict__ rp,
                                               int* __restrict__ bsum) {
  __shared__ int sb[256];
  int t = threadIdx.x, b = blockIdx.x, i = b * 256 + t;
  int d = (i < NN) ? deg[i] : 0;
  sb[t] = d;
  __syncthreads();
#pragma unroll
  for (int off = 1; off < 256; off <<= 1) {
    int v = (t >= off) ? sb[t - off] : 0;
    __syncthreads();
    sb[t] += v;
    __syncthreads();
  }
  if (i < NN) rp[i] = sb[t] - d;
  if (t == 255) bsum[b] = sb[255];
}

// Block-total scan + graph-start binary searches fused (one small block).
__global__ __launch_bounds__(256) void scanB_k(const int* __restrict__ bsum,
                                               int* __restrict__ boff,
                                               const int* __restrict__ batch,
                                               int* __restrict__ gs) {
  __shared__ int sb[256];
  int t = threadIdx.x;
  int d = (t < NBLK) ? bsum[t] : 0;
  sb[t] = d;
  __syncthreads();
#pragma unroll
  for (int off = 1; off < 256; off <<= 1) {
    int v = (t >= off) ? sb[t - off] : 0;
    __syncthreads();
    sb[t] += v;
    __syncthreads();
  }
  if (t < NBLK) boff[t] = sb[t] - d;
  for (int g = t; g <= GG; g += 256) {
    int lo = 0, hi = NN;
    while (lo < hi) {
      int mid = (lo + hi) >> 1;
      if (batch[mid] < g) lo = mid + 1; else hi = mid;
    }
    gs[g] = lo;
  }
}

__global__ __launch_bounds__(256) void scanC_k(int* __restrict__ rp,
                                               const int* __restrict__ boff,
                                               int* __restrict__ cur) {
  int b = blockIdx.x, i = b * 256 + threadIdx.x;
  if (i < NN) {
    int v = rp[i] + boff[b];
    rp[i] = v;
    cur[i] = v;
  }
  if (i == 0) rp[NN] = ETOT;
}

__global__ __launch_bounds__(256) void scatter_k(const int* __restrict__ ei,
                                                 int* __restrict__ cur,
                                                 int* __restrict__ col) {
  int lo = (blockIdx.x & 7) * DPX, hi = lo + DPX;
  int stride = (gridDim.x >> 3) * 256;
  for (int e = (blockIdx.x >> 3) * 256 + threadIdx.x; e < ETOT; e += stride) {
    int d = (e < EE) ? ei[EE + e] : (e - EE);
    if (d >= lo && d < hi) {
      int s = (e < EE) ? ei[e] : d;
      int pos = atomicAdd(&cur[d], 1);
      col[pos] = s;
    }
  }
}

// ---- Fused per-node: segment-softmax (direct exp) + weighted agg
//      (uint4 gather, 4 edge slots, unroll 4 -> 16 edges in flight/wave)
//      + bias+LN+LeakyReLU ----
__global__ __launch_bounds__(256) void agg_k(const int* __restrict__ rp,
                                             const int* __restrict__ col,
                                             const float* __restrict__ als,
                                             const float* __restrict__ ald,
                                             const unsigned short* __restrict__ Hb,
                                             const float* __restrict__ bias,
                                             const float* __restrict__ gamma,
                                             const float* __restrict__ beta,
                                             float* __restrict__ outb) {
  __shared__ float salpha[4][4][68];  // stride 68: max 2-way bank alias (free)
  __shared__ int   scol[4][64];
  int wave = threadIdx.x >> 6, lane = threadIdx.x & 63;
  int n = blockIdx.x * 4 + wave;
  if (n >= NN) return;
  int e0 = rp[n], e1 = rp[n + 1];
  int deg = e1 - e0;
  float4 ad = *(const float4*)&ald[(size_t)n * 4];

  if (deg <= 64) {
    // --- softmax: one edge per lane, direct exp (clamp@60) ---
    int sn = (lane < deg) ? col[e0 + lane] : -1;
    float4 as;
    if (sn >= 0) as = *(const float4*)&als[(size_t)sn * 4];
    else         as = make_float4(0.f, 0.f, 0.f, 0.f);
    float v0 = as.x + ad.x, v1 = as.y + ad.y, v2 = as.z + ad.z, v3 = as.w + ad.w;
    v0 = v0 > 0.f ? v0 : 0.2f * v0;
    v1 = v1 > 0.f ? v1 : 0.2f * v1;
    v2 = v2 > 0.f ? v2 : 0.2f * v2;
    v3 = v3 > 0.f ? v3 : 0.2f * v3;
    float p0 = (sn >= 0) ? __expf(fminf(v0, 60.f)) : 0.f;
    float p1 = (sn >= 0) ? __expf(fminf(v1, 60.f)) : 0.f;
    float p2 = (sn >= 0) ? __expf(fminf(v2, 60.f)) : 0.f;
    float p3 = (sn >= 0) ? __expf(fminf(v3, 60.f)) : 0.f;
    float s0 = p0, s1 = p1, s2 = p2, s3 = p3;
#pragma unroll
    for (int off = 32; off; off >>= 1) {
      s0 += __shfl_xor(s0, off);
      s1 += __shfl_xor(s1, off);
      s2 += __shfl_xor(s2, off);
      s3 += __shfl_xor(s3, off);
    }
    scol[wave][lane] = sn;
    salpha[wave][0][lane] = __fdividef(p0, s0);
    salpha[wave][1][lane] = __fdividef(p1, s1);
    salpha[wave][2][lane] = __fdividef(p2, s2);
    salpha[wave][3][lane] = __fdividef(p3, s3);
    asm volatile("s_waitcnt lgkmcnt(0)" ::: "memory");

    // --- gather: sub = lane>>4 (4 edge slots), fl = lane&15 (8 feats/lane) ---
    int sub = lane >> 4, fl = lane & 15;
    int hh2 = fl >> 2;  // head of this feature octet
    float b0 = 0.f, b1 = 0.f, b2 = 0.f, b3 = 0.f;
    float b4 = 0.f, b5 = 0.f, b6 = 0.f, b7 = 0.f;
#pragma unroll 4
    for (int j = sub; j < deg; j += 4) {
      int snj = scol[wave][j];
      float alpha = salpha[wave][hh2][j];
      uint4 pck = *(const uint4*)&Hb[(size_t)snj * DD + fl * 8];
      b0 = __fmaf_rn(alpha, __uint_as_float(pck.x << 16), b0);
      b1 = __fmaf_rn(alpha, __uint_as_float(pck.x & 0xFFFF0000u), b1);
      b2 = __fmaf_rn(alpha, __uint_as_float(pck.y << 16), b2);
      b3 = __fmaf_rn(alpha, __uint_as_float(pck.y & 0xFFFF0000u), b3);
      b4 = __fmaf_rn(alpha, __uint_as_float(pck.z << 16), b4);
      b5 = __fmaf_rn(alpha, __uint_as_float(pck.z & 0xFFFF0000u), b5);
      b6 = __fmaf_rn(alpha, __uint_as_float(pck.w << 16), b6);
      b7 = __fmaf_rn(alpha, __uint_as_float(pck.w & 0xFFFF0000u), b7);
    }
    // combine the 4 edge-slot partials (lanes L, L^16, L^32, L^48 share features)
    b0 += __shfl_xor(b0, 32); b0 += __shfl_xor(b0, 16);
    b1 += __shfl_xor(b1, 32); b1 += __shfl_xor(b1, 16);
    b2 += __shfl_xor(b2, 32); b2 += __shfl_xor(b2, 16);
    b3 += __shfl_xor(b3, 32); b3 += __shfl_xor(b3, 16);
    b4 += __shfl_xor(b4, 32); b4 += __shfl_xor(b4, 16);
    b5 += __shfl_xor(b5, 32); b5 += __shfl_xor(b5, 16);
    b6 += __shfl_xor(b6, 32); b6 += __shfl_xor(b6, 16);
    b7 += __shfl_xor(b7, 32); b7 += __shfl_xor(b7, 16);

    // bias + LayerNorm + LeakyReLU; values duplicated across subs, reduce over 16 lanes
    int f8 = fl * 8;
    float4 biA = *(const float4*)&bias[f8];
    float4 biB = *(const float4*)&bias[f8 + 4];
    float x0 = b0 + biA.x, x1 = b1 + biA.y, x2 = b2 + biA.z, x3 = b3 + biA.w;
    float x4 = b4 + biB.x, x5 = b5 + biB.y, x6 = b6 + biB.z, x7 = b7 + biB.w;
    float sum = x0 + x1 + x2 + x3 + x4 + x5 + x6 + x7;
    float ssq = x0 * x0 + x1 * x1 + x2 * x2 + x3 * x3 +
                x4 * x4 + x5 * x5 + x6 * x6 + x7 * x7;
#pragma unroll
    for (int off = 8; off; off >>= 1) {
      sum += __shfl_xor(sum, off);
      ssq += __shfl_xor(ssq, off);
    }
    float mu = sum * (1.f / 128.f);
    float var = ssq * (1.f / 128.f) - mu * mu;
    float rstd = rsqrtf(var + 1e-5f);
    float4 gaA = *(const float4*)&gamma[f8];
    float4 gaB = *(const float4*)&gamma[f8 + 4];
    float4 beA = *(const float4*)&beta[f8];
    float4 beB = *(const float4*)&beta[f8 + 4];
    float y0 = (x0 - mu) * rstd * gaA.x + beA.x;
    float y1 = (x1 - mu) * rstd * gaA.y + beA.y;
    float y2 = (x2 - mu) * rstd * gaA.z + beA.z;
    float y3 = (x3 - mu) * rstd * gaA.w + beA.w;
    float y4 = (x4 - mu) * rstd * gaB.x + beB.x;
    float y5 = (x5 - mu) * rstd * gaB.y + beB.y;
    float y6 = (x6 - mu) * rstd * gaB.z + beB.z;
    float y7 = (x7 - mu) * rstd * gaB.w + beB.w;
    y0 = y0 > 0.f ? y0 : 0.1f * y0;
    y1 = y1 > 0.f ? y1 : 0.1f * y1;
    y2 = y2 > 0.f ? y2 : 0.1f * y2;
    y3 = y3 > 0.f ? y3 : 0.1f * y3;
    y4 = y4 > 0.f ? y4 : 0.1f * y4;
    y5 = y5 > 0.f ? y5 : 0.1f * y5;
    y6 = y6 > 0.f ? y6 : 0.1f * y6;
    y7 = y7 > 0.f ? y7 : 0.1f * y7;
    if (sub == 0) {
      float4 oA = {y0, y1, y2, y3};
      float4 oB = {y4, y5, y6, y7};
      *(float4*)&outb[(size_t)n * DD + f8] = oA;
      *(float4*)&outb[(size_t)n * DD + f8 + 4] = oB;
    }
  } else {
    // --- fallback: two-pass direct-exp, 2 feats/lane (deg>64; ~never taken) ---
    int hh = lane >> 4;
    float a0 = 0.f, a1 = 0.f;
    float s[4] = {0.f, 0.f, 0.f, 0.f};
    for (int e = e0 + lane; e < e1; e += 64) {
      int sn = col[e];
      float4 as = *(const float4*)&als[(size_t)sn * 4];
      float v[4] = {as.x + ad.x, as.y + ad.y, as.z + ad.z, as.w + ad.w};
#pragma unroll
      for (int h = 0; h < 4; ++h) {
        float vv = v[h] > 0.f ? v[h] : 0.2f * v[h];
        s[h] += __expf(fminf(vv, 60.f));
      }
    }
#pragma unroll
    for (int off = 32; off; off >>= 1) {
#pragma unroll
      for (int h = 0; h < 4; ++h) s[h] += __shfl_xor(s[h], off);
    }
    float rdh = __fdividef(1.f, s[hh]);
    float adh = (hh == 0) ? ad.x : (hh == 1) ? ad.y : (hh == 2) ? ad.z : ad.w;
    int e = e0;
    while (e < e1) {
      int cnt = min(64, e1 - e);
      int myS = (lane < cnt) ? col[e + lane] : 0;
      for (int j = 0; j < cnt; ++j) {
        int sn = __shfl(myS, j);
        float v = als[(size_t)sn * 4 + hh] + adh;
        v = v > 0.f ? v : 0.2f * v;
        float alpha = __expf(fminf(v, 60.f)) * rdh;
        unsigned pck = *(const unsigned*)&Hb[(size_t)sn * DD + 2 * lane];
        float h0 = __uint_as_float(pck << 16);
        float h1 = __uint_as_float(pck & 0xFFFF0000u);
        a0 = __fmaf_rn(alpha, h0, a0);
        a1 = __fmaf_rn(alpha, h1, a1);
      }
      e += cnt;
    }
    int f0 = 2 * lane, f1 = 2 * lane + 1;
    float x0 = a0 + bias[f0], x1 = a1 + bias[f1];
    float sum = x0 + x1, ssq = x0 * x0 + x1 * x1;
#pragma unroll
    for (int off = 32; off; off >>= 1) {
      sum += __shfl_xor(sum, off);
      ssq += __shfl_xor(ssq, off);
    }
    float mu = sum * (1.f / 128.f);
    float var = ssq * (1.f / 128.f) - mu * mu;
    float rstd = rsqrtf(var + 1e-5f);
    float y0 = (x0 - mu) * rstd * gamma[f0] + beta[f0];
    float y1 = (x1 - mu) * rstd * gamma[f1] + beta[f1];
    y0 = y0 > 0.f ? y0 : 0.1f * y0;
    y1 = y1 > 0.f ? y1 : 0.1f * y1;
    float2 o = {y0, y1};
    *(float2*)&outb[(size_t)n * DD + f0] = o;
  }
}

// ---- Fused pooling + output GEMM ----
__global__ __launch_bounds__(256) void poolout_k(const float* __restrict__ xin,
                                                 const int* __restrict__ gs,
                                                 const float* __restrict__ Wout,
                                                 const float* __restrict__ bout,
                                                 float* __restrict__ out) {
  __shared__ float sp[256];
  __shared__ float r0[256], r1[256];
  int g = blockIdx.x, t = threadIdx.x;
  int f = t & 127, half = t >> 7;
  int n0 = gs[g], n1 = gs[g + 1];
  int cnt = n1 - n0;
  int mid = n0 + (cnt >> 1);
  int a = half ? mid : n0;
  int b = half ? n1 : mid;
  float mx = NEG_SENT, sm = 0.f;
  for (int n = a; n < b; ++n) {
    float v = xin[(size_t)n * DD + f];
    mx = fmaxf(mx, v);
    sm += v;
  }
  r0[t] = mx;
  r1[t] = sm;
  __syncthreads();
  if (t < 128) {
    sp[t] = fmaxf(r0[t], r0[t + 128]);
    sp[128 + t] = (r1[t] + r1[t + 128]) / fmaxf((float)cnt, 1.f);
  }
  __syncthreads();
  float acc = half ? 0.f : bout[f];
  int k0 = half * 128;
#pragma unroll 8
  for (int k = k0; k < k0 + 128; ++k) acc = __fmaf_rn(sp[k], Wout[k * 128 + f], acc);
  r0[t] = acc;
  __syncthreads();
  if (t < 128) out[(size_t)g * 128 + f] = r0[t] + r0[t + 128];
}

extern "C" void kernel_launch(void* const* d_in, const int* in_sizes, int n_in,
                              void* d_out, int out_size, void* d_ws, size_t ws_size,
                              hipStream_t stream) {
  const float* x       = (const float*)d_in[0];
  const int*   ei      = (const int*)d_in[1];
  const int*   batch   = (const int*)d_in[2];
  const float* W       = (const float*)d_in[3];
  const float* att_src = (const float*)d_in[4];
  const float* att_dst = (const float*)d_in[5];
  const float* bias    = (const float*)d_in[6];
  const float* gamma   = (const float*)d_in[7];
  const float* beta    = (const float*)d_in[8];
  const float* Wout    = (const float*)d_in[9];
  const float* bout    = (const float*)d_in[10];
  float* out = (float*)d_out;

  char* ws = (char*)d_ws;
  unsigned short* Hb = (unsigned short*)ws; ws += (size_t)NN * DD * 2;
  float* AB   = (float*)ws; ws += (size_t)NN * DD * 4;
  float* als  = (float*)ws; ws += (size_t)NN * HH * 4;
  float* ald  = (float*)ws; ws += (size_t)NN * HH * 4;
  int*   rp   = (int*)ws;   ws += (size_t)(NN + 1) * 4;
  int*   deg  = (int*)ws;   ws += (size_t)NN * 4;      // reused as scatter cursor
  int*   col  = (int*)ws;   ws += (size_t)ETOT * 4;
  int*   gs   = (int*)ws;   ws += (size_t)(GG + 1) * 4;
  int*   bsum = (int*)ws;   ws += (size_t)NBLK * 4;
  int*   boff = (int*)ws;   ws += (size_t)NBLK * 4;

  // ---- CSR build + graph offsets (once) ----
  hipMemsetAsync(deg, 0, (size_t)NN * 4, stream);
  deg_k<<<CSRB, 256, 0, stream>>>(ei, deg);
  scanA_k<<<NBLK, 256, 0, stream>>>(deg, rp, bsum);
  scanB_k<<<1, 256, 0, stream>>>(bsum, boff, batch, gs);
  scanC_k<<<NBLK, 256, 0, stream>>>(rp, boff, deg);
  scatter_k<<<CSRB, 256, 0, stream>>>(ei, deg, col);

  // ---- layers ----
  const float* in = x;
  for (int l = 0; l < LL; ++l) {
    gemm_al_k<<<(NN + 31) / 32, 256, 0, stream>>>(in, W + (size_t)l * DD * DD,
                                                  att_src + l * DD, att_dst + l * DD,
                                                  Hb, als, ald);
    agg_k<<<(NN + 3) / 4, 256, 0, stream>>>(rp, col, als, ald, Hb,
                                            bias + l * DD, gamma + l * DD, beta + l * DD, AB);
    in = AB;
  }

  // ---- fused pooling + output GEMM ----
  poolout_k<<<GG, 256, 0, stream>>>(AB, gs, Wout, bout, out);
}

// Round 13
// 358.329 us; speedup vs baseline: 1.0690x; 1.0048x over previous
//
#include <hip/hip_runtime.h>

#define NN 50000
#define EE 800000
#define ETOT (EE + NN)
#define GG 256
#define LL 3
#define HH 4
#define DD 128
#define NBLK ((NN + 255) / 256)   // 196
#define NXCD 8
#define DPX ((NN + NXCD - 1) / NXCD)  // 6250
#define CSRB 1024

#define NEG_SENT (-1e30f)

// float -> bf16 bits (round-nearest-even), finite inputs.
__device__ __forceinline__ unsigned short f2bf(float x) {
  unsigned u = __float_as_uint(x);
  unsigned r = u + 0x7FFFu + ((u >> 16) & 1u);
  return (unsigned short)(r >> 16);
}

// ---- GEMM + attention-logit epilogue (padded sA, bf16 W in LDS) ----
__global__ __launch_bounds__(256) void gemm_al_k(const float* __restrict__ A,
                                                 const float* __restrict__ Wl,
                                                 const float* __restrict__ asrc,
                                                 const float* __restrict__ adst,
                                                 unsigned short* __restrict__ Hb,
                                                 float* __restrict__ al_s,
                                                 float* __restrict__ al_d) {
  __shared__ unsigned short sWb[128 * 128];  // 32 KB bf16
  __shared__ float sA[32][132];              // padded: 132%32=4
  int tid = threadIdx.x;
#pragma unroll
  for (int j = 0; j < 16; ++j) {
    int idx = j * 256 + tid;
    float4 v = *(const float4*)&Wl[idx * 4];
    uint2 p;
    p.x = (unsigned)f2bf(v.x) | ((unsigned)f2bf(v.y) << 16);
    p.y = (unsigned)f2bf(v.z) | ((unsigned)f2bf(v.w) << 16);
    *(uint2*)&sWb[idx * 4] = p;
  }
  int row0 = blockIdx.x * 32;
#pragma unroll
  for (int j = 0; j < 4; ++j) {
    int idx = j * 256 + tid;
    int r = idx >> 5, c4 = idx & 31;
    int gr = row0 + r;
    float4 v = (gr < NN) ? *(const float4*)&A[(size_t)gr * DD + c4 * 4]
                         : make_float4(0.f, 0.f, 0.f, 0.f);
    *(float4*)&sA[r][c4 * 4] = v;
  }
  __syncthreads();
  int tc = tid & 31;
  int tr = tid >> 5;
  float acc[4][4] = {};
  for (int k = 0; k < 128; ++k) {
    uint2 wp = *(const uint2*)&sWb[k * 128 + tc * 4];
    float w0 = __uint_as_float(wp.x << 16);
    float w1 = __uint_as_float(wp.x & 0xFFFF0000u);
    float w2 = __uint_as_float(wp.y << 16);
    float w3 = __uint_as_float(wp.y & 0xFFFF0000u);
    float a[4];
#pragma unroll
    for (int r = 0; r < 4; ++r) a[r] = sA[tr * 4 + r][k];
#pragma unroll
    for (int r = 0; r < 4; ++r) {
      acc[r][0] = __fmaf_rn(a[r], w0, acc[r][0]);
      acc[r][1] = __fmaf_rn(a[r], w1, acc[r][1]);
      acc[r][2] = __fmaf_rn(a[r], w2, acc[r][2]);
      acc[r][3] = __fmaf_rn(a[r], w3, acc[r][3]);
    }
  }
  float4 as4 = *(const float4*)&asrc[tc * 4];
  float4 ad4 = *(const float4*)&adst[tc * 4];
  int hg = tc >> 3;
  float ps[4], pd[4];
#pragma unroll
  for (int r = 0; r < 4; ++r) {
    ps[r] = acc[r][0] * as4.x + acc[r][1] * as4.y + acc[r][2] * as4.z + acc[r][3] * as4.w;
    pd[r] = acc[r][0] * ad4.x + acc[r][1] * ad4.y + acc[r][2] * ad4.z + acc[r][3] * ad4.w;
  }
#pragma unroll
  for (int off = 4; off; off >>= 1) {
#pragma unroll
    for (int r = 0; r < 4; ++r) {
      ps[r] += __shfl_xor(ps[r], off);
      pd[r] += __shfl_xor(pd[r], off);
    }
  }
#pragma unroll
  for (int r = 0; r < 4; ++r) {
    int gr = row0 + tr * 4 + r;
    if (gr < NN) {
      unsigned lo = (unsigned)f2bf(acc[r][0]) | ((unsigned)f2bf(acc[r][1]) << 16);
      unsigned hi = (unsigned)f2bf(acc[r][2]) | ((unsigned)f2bf(acc[r][3]) << 16);
      uint2 w = {lo, hi};
      *(uint2*)&Hb[(size_t)gr * DD + tc * 4] = w;
      if ((tc & 7) == 0) {
        al_s[gr * 4 + hg] = ps[r];
        al_d[gr * 4 + hg] = pd[r];
      }
    }
  }
}

// ---- CSR build: XCD-affine dst-range partitioning ----
__global__ __launch_bounds__(256) void deg_k(const int* __restrict__ ei,
                                             int* __restrict__ deg) {
  int lo = (blockIdx.x & 7) * DPX, hi = lo + DPX;
  int stride = (gridDim.x >> 3) * 256;
  for (int e = (blockIdx.x >> 3) * 256 + threadIdx.x; e < ETOT; e += stride) {
    int d = (e < EE) ? ei[EE + e] : (e - EE);
    if (d >= lo && d < hi) atomicAdd(&deg[d], 1);
  }
}

// Local block scan; writes LOCAL exclusive prefix into rp (and in-place into
// deg, which becomes the scatter cursor). rp[NN] gets the block-195 local sum.
__global__ __launch_bounds__(256) void scanA_k(int* __restrict__ deg,
                                               int* __restrict__ rp,
                                               int* __restrict__ bsum) {
  __shared__ int sb[256];
  int t = threadIdx.x, b = blockIdx.x, i = b * 256 + t;
  int d = (i < NN) ? deg[i] : 0;
  sb[t] = d;
  __syncthreads();
#pragma unroll
  for (int off = 1; off < 256; off <<= 1) {
    int v = (t >= off) ? sb[t - off] : 0;
    __syncthreads();
    sb[t] += v;
    __syncthreads();
  }
  int loc = sb[t] - d;
  if (i <= NN) rp[i] = loc;
  if (i < NN) deg[i] = loc;   // scatter cursor (local)
  if (t == 255) bsum[b] = sb[255];
}

// Block-total scan + graph-start binary searches fused (one small block).
__global__ __launch_bounds__(256) void scanB_k(const int* __restrict__ bsum,
                                               int* __restrict__ boff,
                                               const int* __restrict__ batch,
                                               int* __restrict__ gs) {
  __shared__ int sb[256];
  int t = threadIdx.x;
  int d = (t < NBLK) ? bsum[t] : 0;
  sb[t] = d;
  __syncthreads();
#pragma unroll
  for (int off = 1; off < 256; off <<= 1) {
    int v = (t >= off) ? sb[t - off] : 0;
    __syncthreads();
    sb[t] += v;
    __syncthreads();
  }
  if (t < NBLK) boff[t] = sb[t] - d;
  for (int g = t; g <= GG; g += 256) {
    int lo = 0, hi = NN;
    while (lo < hi) {
      int mid = (lo + hi) >> 1;
      if (batch[mid] < g) lo = mid + 1; else hi = mid;
    }
    gs[g] = lo;
  }
}

// Scatter with inline global offset: pos = localCursor(d)++ + boff[d>>8].
// col stored as ushort (src < 65536).
__global__ __launch_bounds__(256) void scatter_k(const int* __restrict__ ei,
                                                 int* __restrict__ cur,
                                                 const int* __restrict__ boff,
                                                 unsigned short* __restrict__ col) {
  int lo = (blockIdx.x & 7) * DPX, hi = lo + DPX;
  int stride = (gridDim.x >> 3) * 256;
  for (int e = (blockIdx.x >> 3) * 256 + threadIdx.x; e < ETOT; e += stride) {
    int d = (e < EE) ? ei[EE + e] : (e - EE);
    if (d >= lo && d < hi) {
      int s = (e < EE) ? ei[e] : d;
      int pos = atomicAdd(&cur[d], 1) + boff[d >> 8];
      col[pos] = (unsigned short)s;
    }
  }
}

// ---- Fused per-node: segment-softmax (direct exp) + weighted agg
//      (uint4 gather, 4 edge slots) + bias+LN+LeakyReLU ----
// Edge range: e = rpLocal[n] + boff[n>>8]  (scanC eliminated).
__global__ __launch_bounds__(256) void agg_k(const int* __restrict__ rp,
                                             const int* __restrict__ boff,
                                             const unsigned short* __restrict__ col,
                                             const float* __restrict__ als,
                                             const float* __restrict__ ald,
                                             const unsigned short* __restrict__ Hb,
                                             const float* __restrict__ bias,
                                             const float* __restrict__ gamma,
                                             const float* __restrict__ beta,
                                             float* __restrict__ outb) {
  __shared__ float salpha[4][4][68];  // stride 68: max 2-way bank alias (free)
  __shared__ int   scol[4][64];
  int wave = threadIdx.x >> 6, lane = threadIdx.x & 63;
  int n = blockIdx.x * 4 + wave;
  if (n >= NN) return;
  int e0 = rp[n] + boff[n >> 8];
  int e1 = rp[n + 1] + boff[(n + 1) >> 8];
  int deg = e1 - e0;
  float4 ad = *(const float4*)&ald[(size_t)n * 4];

  if (deg <= 64) {
    // --- softmax: one edge per lane, direct exp (clamp@60) ---
    int sn = (lane < deg) ? (int)col[e0 + lane] : -1;
    float4 as;
    if (sn >= 0) as = *(const float4*)&als[(size_t)sn * 4];
    else         as = make_float4(0.f, 0.f, 0.f, 0.f);
    float v0 = as.x + ad.x, v1 = as.y + ad.y, v2 = as.z + ad.z, v3 = as.w + ad.w;
    v0 = v0 > 0.f ? v0 : 0.2f * v0;
    v1 = v1 > 0.f ? v1 : 0.2f * v1;
    v2 = v2 > 0.f ? v2 : 0.2f * v2;
    v3 = v3 > 0.f ? v3 : 0.2f * v3;
    float p0 = (sn >= 0) ? __expf(fminf(v0, 60.f)) : 0.f;
    float p1 = (sn >= 0) ? __expf(fminf(v1, 60.f)) : 0.f;
    float p2 = (sn >= 0) ? __expf(fminf(v2, 60.f)) : 0.f;
    float p3 = (sn >= 0) ? __expf(fminf(v3, 60.f)) : 0.f;
    float s0 = p0, s1 = p1, s2 = p2, s3 = p3;
#pragma unroll
    for (int off = 32; off; off >>= 1) {
      s0 += __shfl_xor(s0, off);
      s1 += __shfl_xor(s1, off);
      s2 += __shfl_xor(s2, off);
      s3 += __shfl_xor(s3, off);
    }
    scol[wave][lane] = sn;
    salpha[wave][0][lane] = __fdividef(p0, s0);
    salpha[wave][1][lane] = __fdividef(p1, s1);
    salpha[wave][2][lane] = __fdividef(p2, s2);
    salpha[wave][3][lane] = __fdividef(p3, s3);
    asm volatile("s_waitcnt lgkmcnt(0)" ::: "memory");

    // --- gather: sub = lane>>4 (4 edge slots), fl = lane&15 (8 feats/lane) ---
    int sub = lane >> 4, fl = lane & 15;
    int hh2 = fl >> 2;  // head of this feature octet
    float b0 = 0.f, b1 = 0.f, b2 = 0.f, b3 = 0.f;
    float b4 = 0.f, b5 = 0.f, b6 = 0.f, b7 = 0.f;
#pragma unroll 4
    for (int j = sub; j < deg; j += 4) {
      int snj = scol[wave][j];
      float alpha = salpha[wave][hh2][j];
      uint4 pck = *(const uint4*)&Hb[(size_t)snj * DD + fl * 8];
      b0 = __fmaf_rn(alpha, __uint_as_float(pck.x << 16), b0);
      b1 = __fmaf_rn(alpha, __uint_as_float(pck.x & 0xFFFF0000u), b1);
      b2 = __fmaf_rn(alpha, __uint_as_float(pck.y << 16), b2);
      b3 = __fmaf_rn(alpha, __uint_as_float(pck.y & 0xFFFF0000u), b3);
      b4 = __fmaf_rn(alpha, __uint_as_float(pck.z << 16), b4);
      b5 = __fmaf_rn(alpha, __uint_as_float(pck.z & 0xFFFF0000u), b5);
      b6 = __fmaf_rn(alpha, __uint_as_float(pck.w << 16), b6);
      b7 = __fmaf_rn(alpha, __uint_as_float(pck.w & 0xFFFF0000u), b7);
    }
    // combine the 4 edge-slot partials (lanes L, L^16, L^32, L^48 share features)
    b0 += __shfl_xor(b0, 32); b0 += __shfl_xor(b0, 16);
    b1 += __shfl_xor(b1, 32); b1 += __shfl_xor(b1, 16);
    b2 += __shfl_xor(b2, 32); b2 += __shfl_xor(b2, 16);
    b3 += __shfl_xor(b3, 32); b3 += __shfl_xor(b3, 16);
    b4 += __shfl_xor(b4, 32); b4 += __shfl_xor(b4, 16);
    b5 += __shfl_xor(b5, 32); b5 += __shfl_xor(b5, 16);
    b6 += __shfl_xor(b6, 32); b6 += __shfl_xor(b6, 16);
    b7 += __shfl_xor(b7, 32); b7 += __shfl_xor(b7, 16);

    // bias + LayerNorm + LeakyReLU; values duplicated across subs, reduce over 16 lanes
    int f8 = fl * 8;
    float4 biA = *(const float4*)&bias[f8];
    float4 biB = *(const float4*)&bias[f8 + 4];
    float x0 = b0 + biA.x, x1 = b1 + biA.y, x2 = b2 + biA.z, x3 = b3 + biA.w;
    float x4 = b4 + biB.x, x5 = b5 + biB.y, x6 = b6 + biB.z, x7 = b7 + biB.w;
    float sum = x0 + x1 + x2 + x3 + x4 + x5 + x6 + x7;
    float ssq = x0 * x0 + x1 * x1 + x2 * x2 + x3 * x3 +
                x4 * x4 + x5 * x5 + x6 * x6 + x7 * x7;
#pragma unroll
    for (int off = 8; off; off >>= 1) {
      sum += __shfl_xor(sum, off);
      ssq += __shfl_xor(ssq, off);
    }
    float mu = sum * (1.f / 128.f);
    float var = ssq * (1.f / 128.f) - mu * mu;
    float rstd = rsqrtf(var + 1e-5f);
    float4 gaA = *(const float4*)&gamma[f8];
    float4 gaB = *(const float4*)&gamma[f8 + 4];
    float4 beA = *(const float4*)&beta[f8];
    float4 beB = *(const float4*)&beta[f8 + 4];
    float y0 = (x0 - mu) * rstd * gaA.x + beA.x;
    float y1 = (x1 - mu) * rstd * gaA.y + beA.y;
    float y2 = (x2 - mu) * rstd * gaA.z + beA.z;
    float y3 = (x3 - mu) * rstd * gaA.w + beA.w;
    float y4 = (x4 - mu) * rstd * gaB.x + beB.x;
    float y5 = (x5 - mu) * rstd * gaB.y + beB.y;
    float y6 = (x6 - mu) * rstd * gaB.z + beB.z;
    float y7 = (x7 - mu) * rstd * gaB.w + beB.w;
    y0 = y0 > 0.f ? y0 : 0.1f * y0;
    y1 = y1 > 0.f ? y1 : 0.1f * y1;
    y2 = y2 > 0.f ? y2 : 0.1f * y2;
    y3 = y3 > 0.f ? y3 : 0.1f * y3;
    y4 = y4 > 0.f ? y4 : 0.1f * y4;
    y5 = y5 > 0.f ? y5 : 0.1f * y5;
    y6 = y6 > 0.f ? y6 : 0.1f * y6;
    y7 = y7 > 0.f ? y7 : 0.1f * y7;
    if (sub == 0) {
      float4 oA = {y0, y1, y2, y3};
      float4 oB = {y4, y5, y6, y7};
      *(float4*)&outb[(size_t)n * DD + f8] = oA;
      *(float4*)&outb[(size_t)n * DD + f8 + 4] = oB;
    }
  } else {
    // --- fallback: two-pass direct-exp, 2 feats/lane (deg>64; ~never taken) ---
    int hh = lane >> 4;
    float a0 = 0.f, a1 = 0.f;
    float s[4] = {0.f, 0.f, 0.f, 0.f};
    for (int e = e0 + lane; e < e1; e += 64) {
      int sn = (int)col[e];
      float4 as = *(const float4*)&als[(size_t)sn * 4];
      float v[4] = {as.x + ad.x, as.y + ad.y, as.z + ad.z, as.w + ad.w};
#pragma unroll
      for (int h = 0; h < 4; ++h) {
        float vv = v[h] > 0.f ? v[h] : 0.2f * v[h];
        s[h] += __expf(fminf(vv, 60.f));
      }
    }
#pragma unroll
    for (int off = 32; off; off >>= 1) {
#pragma unroll
      for (int h = 0; h < 4; ++h) s[h] += __shfl_xor(s[h], off);
    }
    float rdh = __fdividef(1.f, s[hh]);
    float adh = (hh == 0) ? ad.x : (hh == 1) ? ad.y : (hh == 2) ? ad.z : ad.w;
    int e = e0;
    while (e < e1) {
      int cnt = min(64, e1 - e);
      int myS = (lane < cnt) ? (int)col[e + lane] : 0;
      for (int j = 0; j < cnt; ++j) {
        int sn = __shfl(myS, j);
        float v = als[(size_t)sn * 4 + hh] + adh;
        v = v > 0.f ? v : 0.2f * v;
        float alpha = __expf(fminf(v, 60.f)) * rdh;
        unsigned pck = *(const unsigned*)&Hb[(size_t)sn * DD + 2 * lane];
        float h0 = __uint_as_float(pck << 16);
        float h1 = __uint_as_float(pck & 0xFFFF0000u);
        a0 = __fmaf_rn(alpha, h0, a0);
        a1 = __fmaf_rn(alpha, h1, a1);
      }
      e += cnt;
    }
    int f0 = 2 * lane, f1 = 2 * lane + 1;
    float x0 = a0 + bias[f0], x1 = a1 + bias[f1];
    float sum = x0 + x1, ssq = x0 * x0 + x1 * x1;
#pragma unroll
    for (int off = 32; off; off >>= 1) {
      sum += __shfl_xor(sum, off);
      ssq += __shfl_xor(ssq, off);
    }
    float mu = sum * (1.f / 128.f);
    float var = ssq * (1.f / 128.f) - mu * mu;
    float rstd = rsqrtf(var + 1e-5f);
    float y0 = (x0 - mu) * rstd * gamma[f0] + beta[f0];
    float y1 = (x1 - mu) * rstd * gamma[f1] + beta[f1];
    y0 = y0 > 0.f ? y0 : 0.1f * y0;
    y1 = y1 > 0.f ? y1 : 0.1f * y1;
    float2 o = {y0, y1};
    *(float2*)&outb[(size_t)n * DD + f0] = o;
  }
}

// ---- Fused pooling + output GEMM ----
__global__ __launch_bounds__(256) void poolout_k(const float* __restrict__ xin,
                                                 const int* __restrict__ gs,
                                                 const float* __restrict__ Wout,
                                                 const float* __restrict__ bout,
                                                 float* __restrict__ out) {
  __shared__ float sp[256];
  __shared__ float r0[256], r1[256];
  int g = blockIdx.x, t = threadIdx.x;
  int f = t & 127, half = t >> 7;
  int n0 = gs[g], n1 = gs[g + 1];
  int cnt = n1 - n0;
  int mid = n0 + (cnt >> 1);
  int a = half ? mid : n0;
  int b = half ? n1 : mid;
  float mx = NEG_SENT, sm = 0.f;
  for (int n = a; n < b; ++n) {
    float v = xin[(size_t)n * DD + f];
    mx = fmaxf(mx, v);
    sm += v;
  }
  r0[t] = mx;
  r1[t] = sm;
  __syncthreads();
  if (t < 128) {
    sp[t] = fmaxf(r0[t], r0[t + 128]);
    sp[128 + t] = (r1[t] + r1[t + 128]) / fmaxf((float)cnt, 1.f);
  }
  __syncthreads();
  float acc = half ? 0.f : bout[f];
  int k0 = half * 128;
#pragma unroll 8
  for (int k = k0; k < k0 + 128; ++k) acc = __fmaf_rn(sp[k], Wout[k * 128 + f], acc);
  r0[t] = acc;
  __syncthreads();
  if (t < 128) out[(size_t)g * 128 + f] = r0[t] + r0[t + 128];
}

extern "C" void kernel_launch(void* const* d_in, const int* in_sizes, int n_in,
                              void* d_out, int out_size, void* d_ws, size_t ws_size,
                              hipStream_t stream) {
  const float* x       = (const float*)d_in[0];
  const int*   ei      = (const int*)d_in[1];
  const int*   batch   = (const int*)d_in[2];
  const float* W       = (const float*)d_in[3];
  const float* att_src = (const float*)d_in[4];
  const float* att_dst = (const float*)d_in[5];
  const float* bias    = (const float*)d_in[6];
  const float* gamma   = (const float*)d_in[7];
  const float* beta    = (const float*)d_in[8];
  const float* Wout    = (const float*)d_in[9];
  const float* bout    = (const float*)d_in[10];
  float* out = (float*)d_out;

  char* ws = (char*)d_ws;
  unsigned short* Hb = (unsigned short*)ws; ws += (size_t)NN * DD * 2;
  float* AB   = (float*)ws; ws += (size_t)NN * DD * 4;
  float* als  = (float*)ws; ws += (size_t)NN * HH * 4;
  float* ald  = (float*)ws; ws += (size_t)NN * HH * 4;
  int*   rp   = (int*)ws;   ws += (size_t)(NN + 1) * 4;   // LOCAL prefixes
  int*   deg  = (int*)ws;   ws += (size_t)NN * 4;          // histogram -> cursor
  unsigned short* col = (unsigned short*)ws; ws += (((size_t)ETOT * 2 + 3) & ~3ull);
  int*   gs   = (int*)ws;   ws += (size_t)(GG + 1) * 4;
  int*   bsum = (int*)ws;   ws += (size_t)NBLK * 4;
  int*   boff = (int*)ws;   ws += (size_t)NBLK * 4;

  // ---- CSR build + graph offsets (once; 5 dispatches) ----
  hipMemsetAsync(deg, 0, (size_t)NN * 4, stream);
  deg_k<<<CSRB, 256, 0, stream>>>(ei, deg);
  scanA_k<<<NBLK, 256, 0, stream>>>(deg, rp, bsum);
  scanB_k<<<1, 256, 0, stream>>>(bsum, boff, batch, gs);
  scatter_k<<<CSRB, 256, 0, stream>>>(ei, deg, boff, col);

  // ---- layers ----
  const float* in = x;
  for (int l = 0; l < LL; ++l) {
    gemm_al_k<<<(NN + 31) / 32, 256, 0, stream>>>(in, W + (size_t)l * DD * DD,
                                                  att_src + l * DD, att_dst + l * DD,
                                                  Hb, als, ald);
    agg_k<<<(NN + 3) / 4, 256, 0, stream>>>(rp, boff, col, als, ald, Hb,
                                            bias + l * DD, gamma + l * DD, beta + l * DD, AB);
    in = AB;
  }

  // ---- fused pooling + output GEMM ----
  poolout_k<<<GG, 256, 0, stream>>>(AB, gs, Wout, bout, out);
}